// Round 9
// baseline (1425.025 us; speedup 1.0000x reference)
//
#include <hip/hip_runtime.h>
#include <hip/hip_bf16.h>

// FlashFFN: y = nan_to_num(gelu_tanh(x@W1 + b1) @ W2) + b2
// Round 11: OCCUPANCY. r4-r10 all ran 1 block/CU (128KiB LDS, 8-wave
// lockstep): every barrier/vmcnt stall idled the whole CU, and five rounds
// of choreography moved MfmaUtil only 33->45%. This round: 128x128 tile,
// BK=64, 4 waves, LDS=64KiB -> 2 independent blocks/CU. Block B's waves
// fill block A's gate stalls (m97/m114 mechanism) ON TOP of the proven
// r9/r10 data path: contiguous-8-row BK=64 staging, XOR swizzle, 4-phase
// quadrant schedule with counted lgkm(4)/vmcnt(2) gates.
// Per wave: 64x64 out, acc[4][4], 16 b128 reads + 32 MFMA per K64.
// FIFO ledgers re-simulated: prologue 8 loads vmcnt(2); steady state
// lgkm 8->4 per phase, vm queue depth 4 -> gate vmcnt(2) publishes each
// half exactly one phase before first read; dbuf WAR >=2 barriers apart.

using bf16 = __hip_bfloat16;
typedef __attribute__((ext_vector_type(4))) float floatx4;
typedef __attribute__((ext_vector_type(8))) short shortx8;

#define TOKENS 4096   // B*S = 2*2048
#define DMODEL 4096
#define DFF    16384

__device__ __forceinline__ void gload_lds16(const void* g, void* l) {
  __builtin_amdgcn_global_load_lds(
      (const __attribute__((address_space(1))) unsigned int*)g,
      (__attribute__((address_space(3))) unsigned int*)l,
      16, 0, 0);
}

__device__ __forceinline__ unsigned lds_u32(const void* p) {
  return (unsigned)(unsigned long long)(const __attribute__((address_space(3))) char*)p;
}

__device__ __forceinline__ float gelu_tanh(float x) {
  // JAX default gelu (approximate=True, tanh form)
  float z = 0.7978845608028654f * (x + 0.044715f * x * x * x);
  float e = __expf(2.0f * z);   // inf -> t=1, 0 -> t=-1: both limits correct
  float t = 1.0f - 2.0f / (e + 1.0f);
  return 0.5f * x * (1.0f + t);
}

#define DSR(dst, addr, off) \
  asm volatile("ds_read_b128 %0, %1 offset:" #off : "=v"(dst) : "v"(addr))

// ---- pre-pass: f32 -> bf16 cast (layout preserved), 8 elems/thread ----
__global__ void cvt_f32_bf16(const float* __restrict__ in, bf16* __restrict__ out) {
  int i = (blockIdx.x * blockDim.x + threadIdx.x) * 8;
  float4 a = *(const float4*)(in + i);
  float4 b = *(const float4*)(in + i + 4);
  union { shortx8 v; bf16 h[8]; } r;
  r.h[0] = __float2bfloat16(a.x); r.h[1] = __float2bfloat16(a.y);
  r.h[2] = __float2bfloat16(a.z); r.h[3] = __float2bfloat16(a.w);
  r.h[4] = __float2bfloat16(b.x); r.h[5] = __float2bfloat16(b.y);
  r.h[6] = __float2bfloat16(b.z); r.h[7] = __float2bfloat16(b.w);
  *(shortx8*)(out + i) = r.v;
}

// ---- pre-pass: transpose + cast. in [R][C] f32 -> out [C][R] bf16 ----
__global__ void transpose_cvt(const float* __restrict__ in, bf16* __restrict__ out,
                              int R, int C) {
  __shared__ float tile[64][65];
  const int c0 = blockIdx.x * 64, r0 = blockIdx.y * 64;
  const int t = threadIdx.x;
#pragma unroll
  for (int p = 0; p < 4; ++p) {
    int r = p * 16 + (t >> 4);
    int c = (t & 15) * 4;
    float4 v = *(const float4*)(in + (size_t)(r0 + r) * C + c0 + c);
    tile[r][c] = v.x; tile[r][c + 1] = v.y;
    tile[r][c + 2] = v.z; tile[r][c + 3] = v.w;
  }
  __syncthreads();
#pragma unroll
  for (int p = 0; p < 2; ++p) {
    int c = p * 32 + (t >> 3);
    int rb = (t & 7) * 8;
    union { shortx8 v; bf16 h[8]; } u;
#pragma unroll
    for (int j = 0; j < 8; ++j) u.h[j] = __float2bfloat16(tile[rb + j][c]);
    *(shortx8*)(out + (size_t)(c0 + c) * R + r0 + rb) = u.v;
  }
}

// ---- 128x128 BK=64 pipelined GEMM, 2 blocks/CU: C = A @ Bt^T ----
// A [M][K] bf16 row-major, Bt [N][K] bf16 row-major. 4 waves (2Mx2N),
// wave = 64x64 out via 4x4 16x16x32 MFMAs x 2kk. Strided wave tiling:
// row = wr*16 + mi*32, col = wc*16 + ni*32 -> mi/ni{0,1}=h0, {2,3}=h1,
// so half-tile publish gates stay counted (never 0 in-loop).
template <int FUSE_GELU>
__launch_bounds__(256, 2)
__global__ void gemm_bt(const bf16* __restrict__ A, const bf16* __restrict__ Bt,
                        const float* __restrict__ bias, void* __restrict__ Cout,
                        int M, int N, int K) {
  // [dbuf][128 rows][64 k] bf16 each
  __shared__ __align__(16) bf16 As[2 * 128 * 64];   // 32 KiB
  __shared__ __align__(16) bf16 Bs[2 * 128 * 64];   // 32 KiB

  const int tid = threadIdx.x;
  const int wave = tid >> 6;
  const int lane = tid & 63;

  // LLC-aware band mapping, 128-tiles: M/128 == 32 both GEMMs.
  // Band = 512 blocks (32 m-rows x 16 n-tiles); XCD k owns m-rows 4k..4k+3.
  // Bijective: nwg % 512 == 0 (GEMM1 4096, GEMM2 1024).
  const int wg9  = blockIdx.x & 511;
  const int xcd  = wg9 & 7;
  const int slot = wg9 >> 3;             // 0..63
  const int m0 = (4 * xcd + (slot & 3)) * 128;
  const int n0 = ((blockIdx.x >> 9) * 16 + (slot >> 2)) * 128;

  const size_t Ks = (size_t)K;
  const int NT = K >> 6;   // # of BK=64 K-tiles (64 or 256 here)

  // ---- staging: per wave-instr 8 contiguous rows x 128 B (r9, proven) ----
  // lane l -> (row w*8+(l>>3), stored blk l&7); source blk (l&7)^((l>>3)&7).
  // Row groups per matrix: +0,+32 (h0), +64,+96 (h1).
  const int swz = (lane & 7) ^ ((lane >> 3) & 7);
  const bf16* agp = A  + (size_t)(m0 + wave * 8 + (lane >> 3)) * Ks + swz * 8;
  const bf16* bgp = Bt + (size_t)(n0 + wave * 8 + (lane >> 3)) * Ks + swz * 8;

  // ---- fragment-read addressing (r9 formula, proven) ----
  const int wr = wave >> 1, wc = wave & 1;   // 2M x 2N
  const int fr = lane & 15;
  const int q  = lane >> 4;
  const unsigned As0 = lds_u32(As);
  const unsigned Bs0 = lds_u32(Bs);
  const unsigned aK0 = As0 + (unsigned)((wr * 16 + fr) * 128 +
                       (((fr >> 2) & 1) * 64) + ((q ^ (fr & 3)) * 16));
  const unsigned aK1 = aK0 ^ 64u;
  const unsigned bK0 = Bs0 + (unsigned)((wc * 16 + fr) * 128 +
                       (((fr >> 2) & 1) * 64) + ((q ^ (fr & 3)) * 16));
  const unsigned bK1 = bK0 ^ 64u;

  floatx4 acc[4][4] = {};
  shortx8 A0[2][2], A1[2][2], B0[2][2], B1[2][2];   // [kk][frag]

  // ---- prologue: stage tile 0 (A-h0, B-h0, A-h1, B-h1), 8 loads ----
  {
    bf16* lA = As + wave * 512;
    bf16* lB = Bs + wave * 512;
    gload_lds16(agp,            lA);
    gload_lds16(agp + 32 * Ks,  lA + 2048);
    gload_lds16(bgp,            lB);
    gload_lds16(bgp + 32 * Ks,  lB + 2048);
    gload_lds16(agp + 64 * Ks,  lA + 4096);
    gload_lds16(agp + 96 * Ks,  lA + 6144);
    gload_lds16(bgp + 64 * Ks,  lB + 4096);
    gload_lds16(bgp + 96 * Ks,  lB + 6144);
  }
  asm volatile("s_waitcnt vmcnt(2)");   // A-h0,B-h0,A-h1 resident; B-h1 flies
  __builtin_amdgcn_s_barrier();
  // prologue reads (h0): B0 then A0 — FIFO order matches steady state
  DSR(B0[0][0], bK0, 0); DSR(B0[0][1], bK0, 4096);
  DSR(B0[1][0], bK1, 0); DSR(B0[1][1], bK1, 4096);
  DSR(A0[0][0], aK0, 0); DSR(A0[0][1], aK0, 4096);
  DSR(A0[1][0], aK1, 0); DSR(A0[1][1], aK1, 4096);

  for (int t = 0; t < NT; ++t) {
    const unsigned dsel  = (unsigned)(t & 1) << 14;
    const unsigned dseln = (unsigned)((t + 1) & 1) << 14;
    const unsigned a0 = aK0 + dsel,  a1 = aK1 + dsel;
    const unsigned b0 = bK0 + dsel,  b1 = bK1 + dsel;
    const unsigned an0 = aK0 + dseln, an1 = aK1 + dseln;
    const unsigned bn0 = bK0 + dseln, bn1 = bK1 + dseln;
    const bool st = (t + 1 < NT);
    const bf16* gA = agp + (size_t)(t + 1) * 64;
    const bf16* gB = bgp + (size_t)(t + 1) * 64;
    bf16* lA = As + ((t + 1) & 1) * 8192 + wave * 512;
    bf16* lB = Bs + ((t + 1) & 1) * 8192 + wave * 512;

    // ===== ph1: Q1 = A0·B0 -> acc[0..1][0..1]; pre-read A1(t);
    //        stage B-h0(t+1); publish B-h1(t) =====
    DSR(A1[0][0], a0, 8192); DSR(A1[0][1], a0, 12288);
    DSR(A1[1][0], a1, 8192); DSR(A1[1][1], a1, 12288);
    if (st) { gload_lds16(gB, lB); gload_lds16(gB + 32 * Ks, lB + 2048); }
    asm volatile("s_waitcnt lgkmcnt(4)");   // drain B0(t),A0(t); A1 flies
    __builtin_amdgcn_sched_barrier(0);
    __builtin_amdgcn_s_setprio(1);
#pragma unroll
    for (int f = 0; f < 2; ++f)
#pragma unroll
      for (int n = 0; n < 2; ++n) {
        acc[f][n] = __builtin_amdgcn_mfma_f32_16x16x32_bf16(A0[0][f], B0[0][n], acc[f][n], 0, 0, 0);
        acc[f][n] = __builtin_amdgcn_mfma_f32_16x16x32_bf16(A0[1][f], B0[1][n], acc[f][n], 0, 0, 0);
      }
    __builtin_amdgcn_s_setprio(0);
    __builtin_amdgcn_sched_barrier(0);
    if (st) asm volatile("s_waitcnt vmcnt(2)");   // B-h1(t) published
    else    asm volatile("s_waitcnt vmcnt(0)");
    __builtin_amdgcn_s_barrier();

    // ===== ph2: Q2 = A1·B0 -> acc[2..3][0..1]; pre-read B1(t);
    //        stage A-h0(t+1); publish B-h0(t+1) =====
    DSR(B1[0][0], b0, 8192); DSR(B1[0][1], b0, 12288);
    DSR(B1[1][0], b1, 8192); DSR(B1[1][1], b1, 12288);
    if (st) { gload_lds16(gA, lA); gload_lds16(gA + 32 * Ks, lA + 2048); }
    asm volatile("s_waitcnt lgkmcnt(4)");   // drain A1(t); B1 flies
    __builtin_amdgcn_sched_barrier(0);
    __builtin_amdgcn_s_setprio(1);
#pragma unroll
    for (int f = 0; f < 2; ++f)
#pragma unroll
      for (int n = 0; n < 2; ++n) {
        acc[2 + f][n] = __builtin_amdgcn_mfma_f32_16x16x32_bf16(A1[0][f], B0[0][n], acc[2 + f][n], 0, 0, 0);
        acc[2 + f][n] = __builtin_amdgcn_mfma_f32_16x16x32_bf16(A1[1][f], B0[1][n], acc[2 + f][n], 0, 0, 0);
      }
    __builtin_amdgcn_s_setprio(0);
    __builtin_amdgcn_sched_barrier(0);
    if (st) asm volatile("s_waitcnt vmcnt(2)");   // B-h0(t+1) published
    __builtin_amdgcn_s_barrier();

    // ===== ph3: Q3 = A1·B1 -> acc[2..3][2..3]; pre-read B0(t+1);
    //        stage A-h1(t+1); publish A-h0(t+1) =====
    if (st) {
      DSR(B0[0][0], bn0, 0); DSR(B0[0][1], bn0, 4096);
      DSR(B0[1][0], bn1, 0); DSR(B0[1][1], bn1, 4096);
      gload_lds16(gA + 64 * Ks, lA + 4096);
      gload_lds16(gA + 96 * Ks, lA + 6144);
      asm volatile("s_waitcnt lgkmcnt(4)");   // drain B1(t); B0(t+1) flies
    } else {
      asm volatile("s_waitcnt lgkmcnt(0)");   // drain B1(t)
    }
    __builtin_amdgcn_sched_barrier(0);
    __builtin_amdgcn_s_setprio(1);
#pragma unroll
    for (int f = 0; f < 2; ++f)
#pragma unroll
      for (int n = 0; n < 2; ++n) {
        acc[2 + f][2 + n] = __builtin_amdgcn_mfma_f32_16x16x32_bf16(A1[0][f], B1[0][n], acc[2 + f][2 + n], 0, 0, 0);
        acc[2 + f][2 + n] = __builtin_amdgcn_mfma_f32_16x16x32_bf16(A1[1][f], B1[1][n], acc[2 + f][2 + n], 0, 0, 0);
      }
    __builtin_amdgcn_s_setprio(0);
    __builtin_amdgcn_sched_barrier(0);
    if (st) asm volatile("s_waitcnt vmcnt(2)");   // A-h0(t+1) published
    __builtin_amdgcn_s_barrier();

    // ===== ph4: Q4 = A0·B1 -> acc[0..1][2..3]; stage B-h1(t+1);
    //        post-read A0(t+1); publish A-h1(t+1) =====
    if (st) { gload_lds16(gB + 64 * Ks, lB + 4096); gload_lds16(gB + 96 * Ks, lB + 6144); }
    __builtin_amdgcn_s_setprio(1);
#pragma unroll
    for (int f = 0; f < 2; ++f)
#pragma unroll
      for (int n = 0; n < 2; ++n) {
        acc[f][2 + n] = __builtin_amdgcn_mfma_f32_16x16x32_bf16(A0[0][f], B1[0][n], acc[f][2 + n], 0, 0, 0);
        acc[f][2 + n] = __builtin_amdgcn_mfma_f32_16x16x32_bf16(A0[1][f], B1[1][n], acc[f][2 + n], 0, 0, 0);
      }
    __builtin_amdgcn_s_setprio(0);
    __builtin_amdgcn_sched_barrier(0);
    if (st) {   // post-cluster read-ahead: A0(t+1); drains at ph1(t+1) lgkm(4)
      DSR(A0[0][0], an0, 0); DSR(A0[0][1], an0, 4096);
      DSR(A0[1][0], an1, 0); DSR(A0[1][1], an1, 4096);
      asm volatile("s_waitcnt vmcnt(2)");   // A-h1(t+1) published
    }
    __builtin_amdgcn_s_barrier();
  }

  // epilogue. C/D layout (m89/m91): col = lane&15, row = (lane>>4)*4 + reg.
  // strided wave tiling: row = m0+wr*16+mi*32+..., col = n0+wc*16+ni*32+fr
  const int col0 = n0 + wc * 16 + fr;
  const int row0 = m0 + wr * 16 + (lane >> 4) * 4;
#pragma unroll
  for (int ni = 0; ni < 4; ++ni) {
    const int col = col0 + ni * 32;
    const float bv = bias[col];
#pragma unroll
    for (int mi = 0; mi < 4; ++mi) {
#pragma unroll
      for (int r = 0; r < 4; ++r) {
        const int row = row0 + mi * 32 + r;
        float v = acc[mi][ni][r];
        if (FUSE_GELU) {
          v = gelu_tanh(v + bv);
          ((bf16*)Cout)[(size_t)row * N + col] = __float2bfloat16(v);
        } else {
          if (!isfinite(v)) v = 0.0f;   // nan_to_num BEFORE +b2
          ((float*)Cout)[(size_t)row * N + col] = v + bv;
        }
      }
    }
  }
}

extern "C" void kernel_launch(void* const* d_in, const int* in_sizes, int n_in,
                              void* d_out, int out_size, void* d_ws, size_t ws_size,
                              hipStream_t stream) {
  const float* x  = (const float*)d_in[0];
  const float* W1 = (const float*)d_in[1];
  const float* b1 = (const float*)d_in[2];
  const float* W2 = (const float*)d_in[3];
  const float* b2 = (const float*)d_in[4];
  float* out = (float*)d_out;

  // workspace layout (bf16): xb 32MB @0, h 128MB @32MB, w1t 128MB @160MB,
  // w2t 128MB @288MB (total 416 MB)
  char* ws = (char*)d_ws;
  bf16* xb  = (bf16*)(ws);
  bf16* h   = (bf16*)(ws + (size_t)32  * 1024 * 1024);
  bf16* w1t = (bf16*)(ws + (size_t)160 * 1024 * 1024);
  bf16* w2t = (bf16*)(ws + (size_t)288 * 1024 * 1024);

  cvt_f32_bf16<<<(TOKENS * DMODEL / 8) / 256, 256, 0, stream>>>(x, xb);
  transpose_cvt<<<dim3(DFF / 64, DMODEL / 64), 256, 0, stream>>>(W1, w1t, DMODEL, DFF);
  transpose_cvt<<<dim3(DMODEL / 64, DFF / 64), 256, 0, stream>>>(W2, w2t, DFF, DMODEL);

  // GEMM1: h = gelu(x @ W1 + b1)   [4096 x 16384] bf16
  gemm_bt<1><<<dim3((DFF / 128) * (TOKENS / 128)), 256, 0, stream>>>(
      xb, w1t, b1, h, TOKENS, DFF, DMODEL);

  // GEMM2: out = nan_guard(h @ W2) + b2   [4096 x 4096] f32
  gemm_bt<0><<<dim3((DMODEL / 128) * (TOKENS / 128)), 256, 0, stream>>>(
      h, w2t, b2, out, TOKENS, DMODEL, DFF);
}

// Round 10
// 1074.659 us; speedup vs baseline: 1.3260x; 1.3260x over previous
//
#include <hip/hip_runtime.h>
#include <hip/hip_bf16.h>

// FlashFFN: y = nan_to_num(gelu_tanh(x@W1 + b1) @ W2) + b2
// Round 12: r10 base (562us/GEMM best) + DEEPENED staging pipeline.
// r11 falsified the occupancy lever (LDS still capped waves at 8/CU;
// regressed). r10's residual: per-phase vmcnt(2) gates wait on loads
// issued only ONE phase earlier (~1300cy slack vs ~900-1100cy loaded HBM
// latency) — m201's discipline is 3 half-tiles in flight (vmcnt 6 = 2x3).
// Now: stage halves of tile t+1 at {ph4(t-1): B-h0, ph1: A-h0, ph2: A-h1,
// ph3: B-h1}; uniform vmcnt(4) gates; every gated load has 3 phases of
// slack. WAR ledger: each region's overwrite lands >=3 barriers after its
// reads drain at their lgkm gate (cases in comments). Reads, lgkm gates,
// swizzle, band map, epilogue identical to r10 -> bitwise-same output.

using bf16 = __hip_bfloat16;
typedef __attribute__((ext_vector_type(4))) float floatx4;
typedef __attribute__((ext_vector_type(8))) short shortx8;

#define TOKENS 4096   // B*S = 2*2048
#define DMODEL 4096
#define DFF    16384

__device__ __forceinline__ void gload_lds16(const void* g, void* l) {
  __builtin_amdgcn_global_load_lds(
      (const __attribute__((address_space(1))) unsigned int*)g,
      (__attribute__((address_space(3))) unsigned int*)l,
      16, 0, 0);
}

__device__ __forceinline__ unsigned lds_u32(const void* p) {
  return (unsigned)(unsigned long long)(const __attribute__((address_space(3))) char*)p;
}

__device__ __forceinline__ float gelu_tanh(float x) {
  // JAX default gelu (approximate=True, tanh form)
  float z = 0.7978845608028654f * (x + 0.044715f * x * x * x);
  float e = __expf(2.0f * z);   // inf -> t=1, 0 -> t=-1: both limits correct
  float t = 1.0f - 2.0f / (e + 1.0f);
  return 0.5f * x * (1.0f + t);
}

#define DSR(dst, addr, off) \
  asm volatile("ds_read_b128 %0, %1 offset:" #off : "=v"(dst) : "v"(addr))

// ---- pre-pass: f32 -> bf16 cast (layout preserved), 8 elems/thread ----
__global__ void cvt_f32_bf16(const float* __restrict__ in, bf16* __restrict__ out) {
  int i = (blockIdx.x * blockDim.x + threadIdx.x) * 8;
  float4 a = *(const float4*)(in + i);
  float4 b = *(const float4*)(in + i + 4);
  union { shortx8 v; bf16 h[8]; } r;
  r.h[0] = __float2bfloat16(a.x); r.h[1] = __float2bfloat16(a.y);
  r.h[2] = __float2bfloat16(a.z); r.h[3] = __float2bfloat16(a.w);
  r.h[4] = __float2bfloat16(b.x); r.h[5] = __float2bfloat16(b.y);
  r.h[6] = __float2bfloat16(b.z); r.h[7] = __float2bfloat16(b.w);
  *(shortx8*)(out + i) = r.v;
}

// ---- pre-pass: transpose + cast. in [R][C] f32 -> out [C][R] bf16 ----
__global__ void transpose_cvt(const float* __restrict__ in, bf16* __restrict__ out,
                              int R, int C) {
  __shared__ float tile[64][65];
  const int c0 = blockIdx.x * 64, r0 = blockIdx.y * 64;
  const int t = threadIdx.x;
#pragma unroll
  for (int p = 0; p < 4; ++p) {
    int r = p * 16 + (t >> 4);
    int c = (t & 15) * 4;
    float4 v = *(const float4*)(in + (size_t)(r0 + r) * C + c0 + c);
    tile[r][c] = v.x; tile[r][c + 1] = v.y;
    tile[r][c + 2] = v.z; tile[r][c + 3] = v.w;
  }
  __syncthreads();
#pragma unroll
  for (int p = 0; p < 2; ++p) {
    int c = p * 32 + (t >> 3);
    int rb = (t & 7) * 8;
    union { shortx8 v; bf16 h[8]; } u;
#pragma unroll
    for (int j = 0; j < 8; ++j) u.h[j] = __float2bfloat16(tile[rb + j][c]);
    *(shortx8*)(out + (size_t)(c0 + c) * R + r0 + rb) = u.v;
  }
}

// ---- BK=64 deep-pipelined GEMM, 3-phase staging slack: C = A @ Bt^T ----
template <int FUSE_GELU>
__launch_bounds__(512, 2)
__global__ void gemm_bt(const bf16* __restrict__ A, const bf16* __restrict__ Bt,
                        const float* __restrict__ bias, void* __restrict__ Cout,
                        int M, int N, int K) {
  // [dbuf][half][128][64] bf16 each
  __shared__ __align__(16) bf16 As[2 * 2 * 128 * 64];   // 64 KiB
  __shared__ __align__(16) bf16 Bs[2 * 2 * 128 * 64];   // 64 KiB

  const int tid = threadIdx.x;
  const int wave = tid >> 6;
  const int lane = tid & 63;

  // LLC-aware band mapping (r6, kept): nwg % 256 == 0 for both GEMMs.
  const int wg8  = blockIdx.x & 255;
  const int xcd  = wg8 & 7;
  const int slot = wg8 >> 3;
  const int m0 = (2 * xcd + (slot & 1)) * 256;
  const int n0 = ((blockIdx.x >> 8) * 16 + (slot >> 1)) * 256;

  const size_t Ks = (size_t)K;
  const int NT = K >> 6;   // # of BK=64 K-tiles (64 or 256 here)

  // ---- staging addressing (r9, proven): 8 contiguous rows x 128 B ----
  const int swz = (lane & 7) ^ ((lane >> 3) & 7);
  const bf16* agp = A  + (size_t)(m0 + wave * 8 + (lane >> 3)) * Ks + swz * 8;
  const bf16* bgp = Bt + (size_t)(n0 + wave * 8 + (lane >> 3)) * Ks + swz * 8;

  // ---- fragment-read addressing (r9, proven) ----
  const int wr = wave >> 2, wc = wave & 3;   // 2M x 4N
  const int fr = lane & 15;
  const int q  = lane >> 4;
  const unsigned As0 = lds_u32(As);
  const unsigned Bs0 = lds_u32(Bs);
  const unsigned aK0 = As0 + (unsigned)((wr * 16 + fr) * 128 +
                       (((fr >> 2) & 1) * 64) + ((q ^ (fr & 3)) * 16));
  const unsigned aK1 = aK0 ^ 64u;
  const unsigned bK0 = Bs0 + (unsigned)((wc * 16 + fr) * 128 +
                       (((fr >> 2) & 1) * 64) + ((q ^ (fr & 3)) * 16));
  const unsigned bK1 = bK0 ^ 64u;

  floatx4 acc[8][4] = {};
  shortx8 A0[2][4], A1[2][4], B0[2][2], B1[2][2];   // persistent fragments

  // ---- prologue: stage tile 0 (A-h0,B-h0,A-h1,B-h1) + B-h0(tile 1) ----
  {
    bf16* lA = As + wave * 512;
    bf16* lB = Bs + wave * 512;
    gload_lds16(agp,             lA);
    gload_lds16(agp +  64 * Ks,  lA + 4096);
    gload_lds16(bgp,             lB);
    gload_lds16(bgp +  64 * Ks,  lB + 4096);
    gload_lds16(agp + 128 * Ks,  lA + 8192);
    gload_lds16(agp + 192 * Ks,  lA + 12288);
    gload_lds16(bgp + 128 * Ks,  lB + 8192);
    gload_lds16(bgp + 192 * Ks,  lB + 12288);
    if (NT > 1) {   // ph4(-1) event: B-h0(tile 1) into dbuf 1
      bf16* lB1 = Bs + 16384 + wave * 512;
      const bf16* gB1 = bgp + 64;
      gload_lds16(gB1,           lB1);
      gload_lds16(gB1 + 64 * Ks, lB1 + 4096);
    }
  }
  // queue: [Ah0(2),Bh0(2),Ah1(2),Bh1(2),Bh0n(2)] -> drain to 4:
  // Ah0,Bh0 (prologue reads) + Ah1 (ph1 reads) resident; Bh1,Bh0n fly.
  if (NT > 1) asm volatile("s_waitcnt vmcnt(4)");
  else        asm volatile("s_waitcnt vmcnt(2)");
  __builtin_amdgcn_s_barrier();
  // prologue reads: B0(0) then A0(0) — FIFO order matches steady state
  DSR(B0[0][0], bK0, 0); DSR(B0[0][1], bK0, 8192);
  DSR(B0[1][0], bK1, 0); DSR(B0[1][1], bK1, 8192);
  DSR(A0[0][0], aK0, 0);     DSR(A0[0][1], aK0, 4096);
  DSR(A0[0][2], aK0, 8192);  DSR(A0[0][3], aK0, 12288);
  DSR(A0[1][0], aK1, 0);     DSR(A0[1][1], aK1, 4096);
  DSR(A0[1][2], aK1, 8192);  DSR(A0[1][3], aK1, 12288);

  for (int t = 0; t < NT; ++t) {
    const unsigned dsel  = (unsigned)(t & 1) << 15;
    const unsigned dseln = (unsigned)((t + 1) & 1) << 15;
    const unsigned a0 = aK0 + dsel,  a1 = aK1 + dsel;
    const unsigned b0 = bK0 + dsel,  b1 = bK1 + dsel;
    const unsigned an0 = aK0 + dseln, an1 = aK1 + dseln;
    const unsigned bn0 = bK0 + dseln, bn1 = bK1 + dseln;
    const bool st  = (t + 1 < NT);
    const bool st2 = (t + 2 < NT);
    const bf16* gA = agp + (size_t)(t + 1) * 64;
    bf16* lA = As + ((t + 1) & 1) * 16384 + wave * 512;
    bf16* lB = Bs + ((t + 1) & 1) * 16384 + wave * 512;

    // ===== ph1: Q1 = A0·B0 -> acc[0..3][0..1]; pre-read A1(t);
    //        stage A-h0(t+1) [WAR: A-h0(t-1) reads drained ph1(t-1)] =====
    DSR(A1[0][0], a0, 16384); DSR(A1[0][1], a0, 20480);
    DSR(A1[0][2], a0, 24576); DSR(A1[0][3], a0, 28672);
    DSR(A1[1][0], a1, 16384); DSR(A1[1][1], a1, 20480);
    DSR(A1[1][2], a1, 24576); DSR(A1[1][3], a1, 28672);
    if (st) { gload_lds16(gA, lA); gload_lds16(gA + 64 * Ks, lA + 4096); }
    asm volatile("s_waitcnt lgkmcnt(8)");   // drain B0(t),A0(t); A1 flies
    __builtin_amdgcn_sched_barrier(0);
    __builtin_amdgcn_s_setprio(1);
#pragma unroll
    for (int f = 0; f < 4; ++f)
#pragma unroll
      for (int n = 0; n < 2; ++n) {
        acc[f][n] = __builtin_amdgcn_mfma_f32_16x16x32_bf16(A0[0][f], B0[0][n], acc[f][n], 0, 0, 0);
        acc[f][n] = __builtin_amdgcn_mfma_f32_16x16x32_bf16(A0[1][f], B0[1][n], acc[f][n], 0, 0, 0);
      }
    __builtin_amdgcn_s_setprio(0);
    __builtin_amdgcn_sched_barrier(0);
    // publish B-h1(t) (issued ph3(t-1), 3 phases slack):
    // queue [Bh1(t),Bh0(t+1),Ah0(t+1)] -> vmcnt(4)
    if (st) asm volatile("s_waitcnt vmcnt(4)");
    else    asm volatile("s_waitcnt vmcnt(0)");
    __builtin_amdgcn_s_barrier();

    // ===== ph2: Q2 = A1·B0 -> acc[4..7][0..1]; pre-read B1(t);
    //        stage A-h1(t+1) [WAR: A1(t-1) reads drained ph2(t-1)] =====
    DSR(B1[0][0], b0, 16384); DSR(B1[0][1], b0, 24576);
    DSR(B1[1][0], b1, 16384); DSR(B1[1][1], b1, 24576);
    if (st) { gload_lds16(gA + 128 * Ks, lA + 8192); gload_lds16(gA + 192 * Ks, lA + 12288); }
    asm volatile("s_waitcnt lgkmcnt(4)");   // drain A1(t); B1 flies
    __builtin_amdgcn_sched_barrier(0);
    __builtin_amdgcn_s_setprio(1);
#pragma unroll
    for (int f = 0; f < 4; ++f)
#pragma unroll
      for (int n = 0; n < 2; ++n) {
        acc[4 + f][n] = __builtin_amdgcn_mfma_f32_16x16x32_bf16(A1[0][f], B0[0][n], acc[4 + f][n], 0, 0, 0);
        acc[4 + f][n] = __builtin_amdgcn_mfma_f32_16x16x32_bf16(A1[1][f], B0[1][n], acc[4 + f][n], 0, 0, 0);
      }
    __builtin_amdgcn_s_setprio(0);
    __builtin_amdgcn_sched_barrier(0);
    // publish B-h0(t+1) (issued ph4(t-1), 3 phases slack):
    // queue [Bh0(t+1),Ah0(t+1),Ah1(t+1)] -> vmcnt(4)
    if (st) asm volatile("s_waitcnt vmcnt(4)");
    __builtin_amdgcn_s_barrier();

    // ===== ph3: Q3 = A1·B1 -> acc[4..7][2..3]; pre-read B0(t+1);
    //        stage B-h1(t+1) [WAR: B1(t-1) reads drained ph3(t-1)] =====
    if (st) {
      const bf16* gB = bgp + (size_t)(t + 1) * 64;
      DSR(B0[0][0], bn0, 0); DSR(B0[0][1], bn0, 8192);
      DSR(B0[1][0], bn1, 0); DSR(B0[1][1], bn1, 8192);
      gload_lds16(gB + 128 * Ks, lB + 8192);
      gload_lds16(gB + 192 * Ks, lB + 12288);
      asm volatile("s_waitcnt lgkmcnt(4)");   // drain B1(t); B0(t+1) flies
    } else {
      asm volatile("s_waitcnt lgkmcnt(0)");   // drain B1(t)
    }
    __builtin_amdgcn_sched_barrier(0);
    __builtin_amdgcn_s_setprio(1);
#pragma unroll
    for (int f = 0; f < 4; ++f)
#pragma unroll
      for (int n = 0; n < 2; ++n) {
        acc[4 + f][2 + n] = __builtin_amdgcn_mfma_f32_16x16x32_bf16(A1[0][f], B1[0][n], acc[4 + f][2 + n], 0, 0, 0);
        acc[4 + f][2 + n] = __builtin_amdgcn_mfma_f32_16x16x32_bf16(A1[1][f], B1[1][n], acc[4 + f][2 + n], 0, 0, 0);
      }
    __builtin_amdgcn_s_setprio(0);
    __builtin_amdgcn_sched_barrier(0);
    // publish A-h0(t+1) (issued ph1(t), 3 phases slack incl. this one):
    // queue [Ah0(t+1),Ah1(t+1),Bh1(t+1)] -> vmcnt(4)
    if (st) asm volatile("s_waitcnt vmcnt(4)");
    __builtin_amdgcn_s_barrier();

    // ===== ph4: Q4 = A0·B1 -> acc[0..3][2..3];
    //        stage B-h0(t+2) [WAR: B0(t) reads drained ph1(t)];
    //        post-read A0(t+1) =====
    if (st2) {
      const bf16* gB2 = bgp + (size_t)(t + 2) * 64;
      bf16* lB2 = Bs + (t & 1) * 16384 + wave * 512;   // (t+2)&1 == t&1
      gload_lds16(gB2,           lB2);
      gload_lds16(gB2 + 64 * Ks, lB2 + 4096);
    }
    __builtin_amdgcn_s_setprio(1);
#pragma unroll
    for (int f = 0; f < 4; ++f)
#pragma unroll
      for (int n = 0; n < 2; ++n) {
        acc[f][2 + n] = __builtin_amdgcn_mfma_f32_16x16x32_bf16(A0[0][f], B1[0][n], acc[f][2 + n], 0, 0, 0);
        acc[f][2 + n] = __builtin_amdgcn_mfma_f32_16x16x32_bf16(A0[1][f], B1[1][n], acc[f][2 + n], 0, 0, 0);
      }
    __builtin_amdgcn_s_setprio(0);
    __builtin_amdgcn_sched_barrier(0);
    if (st) {   // post-cluster read-ahead: A0(t+1); drains at ph1(t+1) lgkm(8)
      DSR(A0[0][0], an0, 0);     DSR(A0[0][1], an0, 4096);
      DSR(A0[0][2], an0, 8192);  DSR(A0[0][3], an0, 12288);
      DSR(A0[1][0], an1, 0);     DSR(A0[1][1], an1, 4096);
      DSR(A0[1][2], an1, 8192);  DSR(A0[1][3], an1, 12288);
    }
    // publish A-h1(t+1) (issued ph2(t), 3 phases slack):
    // queue [Ah1(t+1),Bh1(t+1),Bh0(t+2)] -> vmcnt(4); tail: 4 -> vmcnt(2)
    if (st2)     asm volatile("s_waitcnt vmcnt(4)");
    else if (st) asm volatile("s_waitcnt vmcnt(2)");
    __builtin_amdgcn_s_barrier();
  }

  // epilogue. C/D layout (m89/m91): col = lane&15, row = (lane>>4)*4 + reg.
  // strided wave tiling: row = m0+wr*16+mi*32+..., col = n0+wc*16+ni*64+fr
  const int col0 = n0 + wc * 16 + fr;
  const int row0 = m0 + wr * 16 + (lane >> 4) * 4;
#pragma unroll
  for (int ni = 0; ni < 4; ++ni) {
    const int col = col0 + ni * 64;
    const float bv = bias[col];
#pragma unroll
    for (int mi = 0; mi < 8; ++mi) {
#pragma unroll
      for (int r = 0; r < 4; ++r) {
        const int row = row0 + mi * 32 + r;
        float v = acc[mi][ni][r];
        if (FUSE_GELU) {
          v = gelu_tanh(v + bv);
          ((bf16*)Cout)[(size_t)row * N + col] = __float2bfloat16(v);
        } else {
          if (!isfinite(v)) v = 0.0f;   // nan_to_num BEFORE +b2
          ((float*)Cout)[(size_t)row * N + col] = v + bv;
        }
      }
    }
  }
}

extern "C" void kernel_launch(void* const* d_in, const int* in_sizes, int n_in,
                              void* d_out, int out_size, void* d_ws, size_t ws_size,
                              hipStream_t stream) {
  const float* x  = (const float*)d_in[0];
  const float* W1 = (const float*)d_in[1];
  const float* b1 = (const float*)d_in[2];
  const float* W2 = (const float*)d_in[3];
  const float* b2 = (const float*)d_in[4];
  float* out = (float*)d_out;

  // workspace layout (bf16): xb 32MB @0, h 128MB @32MB, w1t 128MB @160MB,
  // w2t 128MB @288MB (total 416 MB)
  char* ws = (char*)d_ws;
  bf16* xb  = (bf16*)(ws);
  bf16* h   = (bf16*)(ws + (size_t)32  * 1024 * 1024);
  bf16* w1t = (bf16*)(ws + (size_t)160 * 1024 * 1024);
  bf16* w2t = (bf16*)(ws + (size_t)288 * 1024 * 1024);

  cvt_f32_bf16<<<(TOKENS * DMODEL / 8) / 256, 256, 0, stream>>>(x, xb);
  transpose_cvt<<<dim3(DFF / 64, DMODEL / 64), 256, 0, stream>>>(W1, w1t, DMODEL, DFF);
  transpose_cvt<<<dim3(DMODEL / 64, DFF / 64), 256, 0, stream>>>(W2, w2t, DFF, DMODEL);

  // GEMM1: h = gelu(x @ W1 + b1)   [4096 x 16384] bf16
  gemm_bt<1><<<dim3((DFF / 256) * (TOKENS / 256)), 512, 0, stream>>>(
      xb, w1t, b1, h, TOKENS, DFF, DMODEL);

  // GEMM2: out = nan_guard(h @ W2) + b2   [4096 x 4096] f32
  gemm_bt<0><<<dim3((DMODEL / 256) * (TOKENS / 256)), 512, 0, stream>>>(
      h, w2t, b2, out, TOKENS, DMODEL, DFF);
}

// Round 11
// 1074.175 us; speedup vs baseline: 1.3266x; 1.0005x over previous
//
#include <hip/hip_runtime.h>
#include <hip/hip_bf16.h>

// FlashFFN: y = nan_to_num(gelu_tanh(x@W1 + b1) @ W2) + b2
// Round 13: kk-GROUPED MFMA clusters on the r12 base (best: 1074.7us).
// r12's vmcnt-depth null closed the staging-latency family; register math
// (128 VGPR + 128 AGPR = 256 unified -> 2 waves/SIMD hard cap) closed the
// occupancy family. Remaining suspect: every cluster issued DEPENDENT MFMA
// pairs back-to-back (acc = mfma(kk0); acc = mfma(kk1) on the same acc).
// With 2 waves/SIMD the dependent op re-enters the pipe ~19-39cy after its
// producer; if MFMA C-latency ~35-40cy each pair stalls the matrix pipe.
// Fix: issue all 8 independent kk0 MFMAs, then the 8 kk1 (dep distance 8
// issue slots ~155cy -> hidden). Per-acc order kk0-then-kk1 preserved ->
// bitwise-identical output. Everything else identical to r12.

using bf16 = __hip_bfloat16;
typedef __attribute__((ext_vector_type(4))) float floatx4;
typedef __attribute__((ext_vector_type(8))) short shortx8;

#define TOKENS 4096   // B*S = 2*2048
#define DMODEL 4096
#define DFF    16384

__device__ __forceinline__ void gload_lds16(const void* g, void* l) {
  __builtin_amdgcn_global_load_lds(
      (const __attribute__((address_space(1))) unsigned int*)g,
      (__attribute__((address_space(3))) unsigned int*)l,
      16, 0, 0);
}

__device__ __forceinline__ unsigned lds_u32(const void* p) {
  return (unsigned)(unsigned long long)(const __attribute__((address_space(3))) char*)p;
}

__device__ __forceinline__ float gelu_tanh(float x) {
  // JAX default gelu (approximate=True, tanh form)
  float z = 0.7978845608028654f * (x + 0.044715f * x * x * x);
  float e = __expf(2.0f * z);   // inf -> t=1, 0 -> t=-1: both limits correct
  float t = 1.0f - 2.0f / (e + 1.0f);
  return 0.5f * x * (1.0f + t);
}

#define DSR(dst, addr, off) \
  asm volatile("ds_read_b128 %0, %1 offset:" #off : "=v"(dst) : "v"(addr))

// ---- pre-pass: f32 -> bf16 cast (layout preserved), 8 elems/thread ----
__global__ void cvt_f32_bf16(const float* __restrict__ in, bf16* __restrict__ out) {
  int i = (blockIdx.x * blockDim.x + threadIdx.x) * 8;
  float4 a = *(const float4*)(in + i);
  float4 b = *(const float4*)(in + i + 4);
  union { shortx8 v; bf16 h[8]; } r;
  r.h[0] = __float2bfloat16(a.x); r.h[1] = __float2bfloat16(a.y);
  r.h[2] = __float2bfloat16(a.z); r.h[3] = __float2bfloat16(a.w);
  r.h[4] = __float2bfloat16(b.x); r.h[5] = __float2bfloat16(b.y);
  r.h[6] = __float2bfloat16(b.z); r.h[7] = __float2bfloat16(b.w);
  *(shortx8*)(out + i) = r.v;
}

// ---- pre-pass: transpose + cast. in [R][C] f32 -> out [C][R] bf16 ----
__global__ void transpose_cvt(const float* __restrict__ in, bf16* __restrict__ out,
                              int R, int C) {
  __shared__ float tile[64][65];
  const int c0 = blockIdx.x * 64, r0 = blockIdx.y * 64;
  const int t = threadIdx.x;
#pragma unroll
  for (int p = 0; p < 4; ++p) {
    int r = p * 16 + (t >> 4);
    int c = (t & 15) * 4;
    float4 v = *(const float4*)(in + (size_t)(r0 + r) * C + c0 + c);
    tile[r][c] = v.x; tile[r][c + 1] = v.y;
    tile[r][c + 2] = v.z; tile[r][c + 3] = v.w;
  }
  __syncthreads();
#pragma unroll
  for (int p = 0; p < 2; ++p) {
    int c = p * 32 + (t >> 3);
    int rb = (t & 7) * 8;
    union { shortx8 v; bf16 h[8]; } u;
#pragma unroll
    for (int j = 0; j < 8; ++j) u.h[j] = __float2bfloat16(tile[rb + j][c]);
    *(shortx8*)(out + (size_t)(c0 + c) * R + r0 + rb) = u.v;
  }
}

// ---- BK=64 deep-pipelined GEMM, 3-phase staging slack: C = A @ Bt^T ----
template <int FUSE_GELU>
__launch_bounds__(512, 2)
__global__ void gemm_bt(const bf16* __restrict__ A, const bf16* __restrict__ Bt,
                        const float* __restrict__ bias, void* __restrict__ Cout,
                        int M, int N, int K) {
  // [dbuf][half][128][64] bf16 each
  __shared__ __align__(16) bf16 As[2 * 2 * 128 * 64];   // 64 KiB
  __shared__ __align__(16) bf16 Bs[2 * 2 * 128 * 64];   // 64 KiB

  const int tid = threadIdx.x;
  const int wave = tid >> 6;
  const int lane = tid & 63;

  // LLC-aware band mapping (r6, kept): nwg % 256 == 0 for both GEMMs.
  const int wg8  = blockIdx.x & 255;
  const int xcd  = wg8 & 7;
  const int slot = wg8 >> 3;
  const int m0 = (2 * xcd + (slot & 1)) * 256;
  const int n0 = ((blockIdx.x >> 8) * 16 + (slot >> 1)) * 256;

  const size_t Ks = (size_t)K;
  const int NT = K >> 6;   // # of BK=64 K-tiles (64 or 256 here)

  // ---- staging addressing (r9, proven): 8 contiguous rows x 128 B ----
  const int swz = (lane & 7) ^ ((lane >> 3) & 7);
  const bf16* agp = A  + (size_t)(m0 + wave * 8 + (lane >> 3)) * Ks + swz * 8;
  const bf16* bgp = Bt + (size_t)(n0 + wave * 8 + (lane >> 3)) * Ks + swz * 8;

  // ---- fragment-read addressing (r9, proven) ----
  const int wr = wave >> 2, wc = wave & 3;   // 2M x 4N
  const int fr = lane & 15;
  const int q  = lane >> 4;
  const unsigned As0 = lds_u32(As);
  const unsigned Bs0 = lds_u32(Bs);
  const unsigned aK0 = As0 + (unsigned)((wr * 16 + fr) * 128 +
                       (((fr >> 2) & 1) * 64) + ((q ^ (fr & 3)) * 16));
  const unsigned aK1 = aK0 ^ 64u;
  const unsigned bK0 = Bs0 + (unsigned)((wc * 16 + fr) * 128 +
                       (((fr >> 2) & 1) * 64) + ((q ^ (fr & 3)) * 16));
  const unsigned bK1 = bK0 ^ 64u;

  floatx4 acc[8][4] = {};
  shortx8 A0[2][4], A1[2][4], B0[2][2], B1[2][2];   // persistent fragments

  // ---- prologue: stage tile 0 (A-h0,B-h0,A-h1,B-h1) + B-h0(tile 1) ----
  {
    bf16* lA = As + wave * 512;
    bf16* lB = Bs + wave * 512;
    gload_lds16(agp,             lA);
    gload_lds16(agp +  64 * Ks,  lA + 4096);
    gload_lds16(bgp,             lB);
    gload_lds16(bgp +  64 * Ks,  lB + 4096);
    gload_lds16(agp + 128 * Ks,  lA + 8192);
    gload_lds16(agp + 192 * Ks,  lA + 12288);
    gload_lds16(bgp + 128 * Ks,  lB + 8192);
    gload_lds16(bgp + 192 * Ks,  lB + 12288);
    if (NT > 1) {   // ph4(-1) event: B-h0(tile 1) into dbuf 1
      bf16* lB1 = Bs + 16384 + wave * 512;
      const bf16* gB1 = bgp + 64;
      gload_lds16(gB1,           lB1);
      gload_lds16(gB1 + 64 * Ks, lB1 + 4096);
    }
  }
  // queue: [Ah0(2),Bh0(2),Ah1(2),Bh1(2),Bh0n(2)] -> drain to 4:
  // Ah0,Bh0 (prologue reads) + Ah1 (ph1 reads) resident; Bh1,Bh0n fly.
  if (NT > 1) asm volatile("s_waitcnt vmcnt(4)");
  else        asm volatile("s_waitcnt vmcnt(2)");
  __builtin_amdgcn_s_barrier();
  // prologue reads: B0(0) then A0(0) — FIFO order matches steady state
  DSR(B0[0][0], bK0, 0); DSR(B0[0][1], bK0, 8192);
  DSR(B0[1][0], bK1, 0); DSR(B0[1][1], bK1, 8192);
  DSR(A0[0][0], aK0, 0);     DSR(A0[0][1], aK0, 4096);
  DSR(A0[0][2], aK0, 8192);  DSR(A0[0][3], aK0, 12288);
  DSR(A0[1][0], aK1, 0);     DSR(A0[1][1], aK1, 4096);
  DSR(A0[1][2], aK1, 8192);  DSR(A0[1][3], aK1, 12288);

  for (int t = 0; t < NT; ++t) {
    const unsigned dsel  = (unsigned)(t & 1) << 15;
    const unsigned dseln = (unsigned)((t + 1) & 1) << 15;
    const unsigned a0 = aK0 + dsel,  a1 = aK1 + dsel;
    const unsigned b0 = bK0 + dsel,  b1 = bK1 + dsel;
    const unsigned an0 = aK0 + dseln, an1 = aK1 + dseln;
    const unsigned bn0 = bK0 + dseln, bn1 = bK1 + dseln;
    const bool st  = (t + 1 < NT);
    const bool st2 = (t + 2 < NT);
    const bf16* gA = agp + (size_t)(t + 1) * 64;
    bf16* lA = As + ((t + 1) & 1) * 16384 + wave * 512;
    bf16* lB = Bs + ((t + 1) & 1) * 16384 + wave * 512;

    // ===== ph1: Q1 = A0·B0 -> acc[0..3][0..1]; pre-read A1(t);
    //        stage A-h0(t+1) [WAR: A-h0(t-1) reads drained ph1(t-1)] =====
    DSR(A1[0][0], a0, 16384); DSR(A1[0][1], a0, 20480);
    DSR(A1[0][2], a0, 24576); DSR(A1[0][3], a0, 28672);
    DSR(A1[1][0], a1, 16384); DSR(A1[1][1], a1, 20480);
    DSR(A1[1][2], a1, 24576); DSR(A1[1][3], a1, 28672);
    if (st) { gload_lds16(gA, lA); gload_lds16(gA + 64 * Ks, lA + 4096); }
    asm volatile("s_waitcnt lgkmcnt(8)");   // drain B0(t),A0(t); A1 flies
    __builtin_amdgcn_sched_barrier(0);
    __builtin_amdgcn_s_setprio(1);
    // kk-grouped: 8 independent kk0, then 8 kk1 (dep distance 8 slots)
#pragma unroll
    for (int f = 0; f < 4; ++f)
#pragma unroll
      for (int n = 0; n < 2; ++n)
        acc[f][n] = __builtin_amdgcn_mfma_f32_16x16x32_bf16(A0[0][f], B0[0][n], acc[f][n], 0, 0, 0);
#pragma unroll
    for (int f = 0; f < 4; ++f)
#pragma unroll
      for (int n = 0; n < 2; ++n)
        acc[f][n] = __builtin_amdgcn_mfma_f32_16x16x32_bf16(A0[1][f], B0[1][n], acc[f][n], 0, 0, 0);
    __builtin_amdgcn_s_setprio(0);
    __builtin_amdgcn_sched_barrier(0);
    // publish B-h1(t) (issued ph3(t-1), 3 phases slack):
    if (st) asm volatile("s_waitcnt vmcnt(4)");
    else    asm volatile("s_waitcnt vmcnt(0)");
    __builtin_amdgcn_s_barrier();

    // ===== ph2: Q2 = A1·B0 -> acc[4..7][0..1]; pre-read B1(t);
    //        stage A-h1(t+1) [WAR: A1(t-1) reads drained ph2(t-1)] =====
    DSR(B1[0][0], b0, 16384); DSR(B1[0][1], b0, 24576);
    DSR(B1[1][0], b1, 16384); DSR(B1[1][1], b1, 24576);
    if (st) { gload_lds16(gA + 128 * Ks, lA + 8192); gload_lds16(gA + 192 * Ks, lA + 12288); }
    asm volatile("s_waitcnt lgkmcnt(4)");   // drain A1(t); B1 flies
    __builtin_amdgcn_sched_barrier(0);
    __builtin_amdgcn_s_setprio(1);
#pragma unroll
    for (int f = 0; f < 4; ++f)
#pragma unroll
      for (int n = 0; n < 2; ++n)
        acc[4 + f][n] = __builtin_amdgcn_mfma_f32_16x16x32_bf16(A1[0][f], B0[0][n], acc[4 + f][n], 0, 0, 0);
#pragma unroll
    for (int f = 0; f < 4; ++f)
#pragma unroll
      for (int n = 0; n < 2; ++n)
        acc[4 + f][n] = __builtin_amdgcn_mfma_f32_16x16x32_bf16(A1[1][f], B0[1][n], acc[4 + f][n], 0, 0, 0);
    __builtin_amdgcn_s_setprio(0);
    __builtin_amdgcn_sched_barrier(0);
    // publish B-h0(t+1) (issued ph4(t-1), 3 phases slack):
    if (st) asm volatile("s_waitcnt vmcnt(4)");
    __builtin_amdgcn_s_barrier();

    // ===== ph3: Q3 = A1·B1 -> acc[4..7][2..3]; pre-read B0(t+1);
    //        stage B-h1(t+1) [WAR: B1(t-1) reads drained ph3(t-1)] =====
    if (st) {
      const bf16* gB = bgp + (size_t)(t + 1) * 64;
      DSR(B0[0][0], bn0, 0); DSR(B0[0][1], bn0, 8192);
      DSR(B0[1][0], bn1, 0); DSR(B0[1][1], bn1, 8192);
      gload_lds16(gB + 128 * Ks, lB + 8192);
      gload_lds16(gB + 192 * Ks, lB + 12288);
      asm volatile("s_waitcnt lgkmcnt(4)");   // drain B1(t); B0(t+1) flies
    } else {
      asm volatile("s_waitcnt lgkmcnt(0)");   // drain B1(t)
    }
    __builtin_amdgcn_sched_barrier(0);
    __builtin_amdgcn_s_setprio(1);
#pragma unroll
    for (int f = 0; f < 4; ++f)
#pragma unroll
      for (int n = 0; n < 2; ++n)
        acc[4 + f][2 + n] = __builtin_amdgcn_mfma_f32_16x16x32_bf16(A1[0][f], B1[0][n], acc[4 + f][2 + n], 0, 0, 0);
#pragma unroll
    for (int f = 0; f < 4; ++f)
#pragma unroll
      for (int n = 0; n < 2; ++n)
        acc[4 + f][2 + n] = __builtin_amdgcn_mfma_f32_16x16x32_bf16(A1[1][f], B1[1][n], acc[4 + f][2 + n], 0, 0, 0);
    __builtin_amdgcn_s_setprio(0);
    __builtin_amdgcn_sched_barrier(0);
    // publish A-h0(t+1) (issued ph1(t), 3 phases slack incl. this one):
    if (st) asm volatile("s_waitcnt vmcnt(4)");
    __builtin_amdgcn_s_barrier();

    // ===== ph4: Q4 = A0·B1 -> acc[0..3][2..3];
    //        stage B-h0(t+2) [WAR: B0(t) reads drained ph1(t)];
    //        post-read A0(t+1) =====
    if (st2) {
      const bf16* gB2 = bgp + (size_t)(t + 2) * 64;
      bf16* lB2 = Bs + (t & 1) * 16384 + wave * 512;   // (t+2)&1 == t&1
      gload_lds16(gB2,           lB2);
      gload_lds16(gB2 + 64 * Ks, lB2 + 4096);
    }
    __builtin_amdgcn_s_setprio(1);
#pragma unroll
    for (int f = 0; f < 4; ++f)
#pragma unroll
      for (int n = 0; n < 2; ++n)
        acc[f][2 + n] = __builtin_amdgcn_mfma_f32_16x16x32_bf16(A0[0][f], B1[0][n], acc[f][2 + n], 0, 0, 0);
#pragma unroll
    for (int f = 0; f < 4; ++f)
#pragma unroll
      for (int n = 0; n < 2; ++n)
        acc[f][2 + n] = __builtin_amdgcn_mfma_f32_16x16x32_bf16(A0[1][f], B1[1][n], acc[f][2 + n], 0, 0, 0);
    __builtin_amdgcn_s_setprio(0);
    __builtin_amdgcn_sched_barrier(0);
    if (st) {   // post-cluster read-ahead: A0(t+1); drains at ph1(t+1) lgkm(8)
      DSR(A0[0][0], an0, 0);     DSR(A0[0][1], an0, 4096);
      DSR(A0[0][2], an0, 8192);  DSR(A0[0][3], an0, 12288);
      DSR(A0[1][0], an1, 0);     DSR(A0[1][1], an1, 4096);
      DSR(A0[1][2], an1, 8192);  DSR(A0[1][3], an1, 12288);
    }
    // publish A-h1(t+1) (issued ph2(t), 3 phases slack):
    if (st2)     asm volatile("s_waitcnt vmcnt(4)");
    else if (st) asm volatile("s_waitcnt vmcnt(2)");
    __builtin_amdgcn_s_barrier();
  }

  // epilogue. C/D layout (m89/m91): col = lane&15, row = (lane>>4)*4 + reg.
  // strided wave tiling: row = m0+wr*16+mi*32+..., col = n0+wc*16+ni*64+fr
  const int col0 = n0 + wc * 16 + fr;
  const int row0 = m0 + wr * 16 + (lane >> 4) * 4;
#pragma unroll
  for (int ni = 0; ni < 4; ++ni) {
    const int col = col0 + ni * 64;
    const float bv = bias[col];
#pragma unroll
    for (int mi = 0; mi < 8; ++mi) {
#pragma unroll
      for (int r = 0; r < 4; ++r) {
        const int row = row0 + mi * 32 + r;
        float v = acc[mi][ni][r];
        if (FUSE_GELU) {
          v = gelu_tanh(v + bv);
          ((bf16*)Cout)[(size_t)row * N + col] = __float2bfloat16(v);
        } else {
          if (!isfinite(v)) v = 0.0f;   // nan_to_num BEFORE +b2
          ((float*)Cout)[(size_t)row * N + col] = v + bv;
        }
      }
    }
  }
}

extern "C" void kernel_launch(void* const* d_in, const int* in_sizes, int n_in,
                              void* d_out, int out_size, void* d_ws, size_t ws_size,
                              hipStream_t stream) {
  const float* x  = (const float*)d_in[0];
  const float* W1 = (const float*)d_in[1];
  const float* b1 = (const float*)d_in[2];
  const float* W2 = (const float*)d_in[3];
  const float* b2 = (const float*)d_in[4];
  float* out = (float*)d_out;

  // workspace layout (bf16): xb 32MB @0, h 128MB @32MB, w1t 128MB @160MB,
  // w2t 128MB @288MB (total 416 MB)
  char* ws = (char*)d_ws;
  bf16* xb  = (bf16*)(ws);
  bf16* h   = (bf16*)(ws + (size_t)32  * 1024 * 1024);
  bf16* w1t = (bf16*)(ws + (size_t)160 * 1024 * 1024);
  bf16* w2t = (bf16*)(ws + (size_t)288 * 1024 * 1024);

  cvt_f32_bf16<<<(TOKENS * DMODEL / 8) / 256, 256, 0, stream>>>(x, xb);
  transpose_cvt<<<dim3(DFF / 64, DMODEL / 64), 256, 0, stream>>>(W1, w1t, DMODEL, DFF);
  transpose_cvt<<<dim3(DMODEL / 64, DFF / 64), 256, 0, stream>>>(W2, w2t, DFF, DMODEL);

  // GEMM1: h = gelu(x @ W1 + b1)   [4096 x 16384] bf16
  gemm_bt<1><<<dim3((DFF / 256) * (TOKENS / 256)), 512, 0, stream>>>(
      xb, w1t, b1, h, TOKENS, DFF, DMODEL);

  // GEMM2: out = nan_guard(h @ W2) + b2   [4096 x 4096] f32
  gemm_bt<0><<<dim3((DMODEL / 256) * (TOKENS / 256)), 512, 0, stream>>>(
      h, w2t, b2, out, TOKENS, DMODEL, DFF);
}